// Round 4
// baseline (17565.018 us; speedup 1.0000x reference)
//
#include <hip/hip_runtime.h>
#include <hip/hip_bf16.h>

// EnsembleRSSM observe scan: B=256, T=64, STOCH=32, DETER=1024, HIDDEN=1024,
// EMBED=1536, ACT=6, ENS=5.
// v5: XCD-island persistent kernel. B=256 rows partitioned across 8 XCDs by
// RUNTIME-DISCOVERED XCC_ID (same-L2 by construction). Per-island barriers:
// vmcnt drain + packed 64b count|gen atomic at L3 + buffer_inv (L1-only).
// No agent fences ever (round-2 lesson: threadfence = full L2 wb/inv = 6x slower).
// Zero cross-island data flow after one fence-free startup barrier.
// Eobs (embed half of obs head) precomputed as one big GEMM (v4, verified).

#define B_ 256
#define T_ 64
#define ACT_ 6
#define EMBED_ 1536
#define OUTW_ 1216
#define NBLK 768

typedef __attribute__((ext_vector_type(8))) short bf16x8;
typedef __attribute__((ext_vector_type(4))) float f32x4;

__device__ inline unsigned short f2bf(float x) {
    union { float f; unsigned int u; } v; v.f = x;
    unsigned int r = v.u + 0x7fffu + ((v.u >> 16) & 1u);
    return (unsigned short)(r >> 16);
}
__device__ inline float bf2f(unsigned short h) {
    union { unsigned int u; float f; } v; v.u = ((unsigned int)h) << 16;
    return v.f;
}
__device__ inline float softplus_f(float x) { return x > 20.f ? x : log1pf(expf(x)); }
__device__ inline float sigmoid_f(float x) { return 1.f / (1.f + expf(-x)); }
__device__ inline float elu_f(float x) { return x > 0.f ? x : expm1f(x); }

// ---------------- flat fp32 -> bf16 convert --------------------------------
__global__ __launch_bounds__(256)
void k_convert(const float* __restrict__ src, unsigned short* __restrict__ dst, long n4) {
    for (long i = blockIdx.x * 256 + threadIdx.x; i < n4; i += (long)gridDim.x * 256) {
        f32x4 v = *(const f32x4*)(src + i * 4);
        unsigned short* d = dst + i * 4;
        d[0] = f2bf(v[0]); d[1] = f2bf(v[1]); d[2] = f2bf(v[2]); d[3] = f2bf(v[3]);
    }
}

// ---------------- transpose + fp32->bf16 convert: dst[n][k] = src[k][n] ----
__global__ __launch_bounds__(256)
void k_transpose_cvt(const float* __restrict__ src, unsigned short* __restrict__ dst,
                     int K, int N) {
    __shared__ float tile[32][33];
    size_t off = (size_t)blockIdx.z * K * N;
    src += off; dst += off;
    int n0 = blockIdx.x * 32, k0 = blockIdx.y * 32;
    int tx = threadIdx.x, ty = threadIdx.y;
    for (int i = ty; i < 32; i += 8) tile[i][tx] = src[(size_t)(k0 + i) * N + n0 + tx];
    __syncthreads();
    for (int i = ty; i < 32; i += 8) dst[(size_t)(n0 + i) * K + k0 + tx] = f2bf(tile[tx][i]);
}

// ---------------- MFMA tile with depth-2 register prefetch -----------------
template<int MF, int NF, int KI>
__device__ inline void mfma_tile_db(const unsigned short* __restrict__ A, int lda,
                                    const unsigned short* __restrict__ Bt, int ldb,
                                    int row0, int col0, f32x4 acc[MF][NF]) {
    int lane = threadIdx.x & 63;
    int lr = lane & 15, q = lane >> 4;
    const unsigned short* ap = A + (size_t)(row0 + lr) * lda + q * 8;
    const unsigned short* bp = Bt + (size_t)(col0 + lr) * ldb + q * 8;
    bf16x8 a0[MF], b0[NF], a1[MF], b1[NF], a2[MF], b2[NF];
    auto ld = [&](bf16x8 (&av)[MF], bf16x8 (&bv)[NF], int kk) {
#pragma unroll
        for (int i = 0; i < MF; i++) av[i] = *(const bf16x8*)(ap + (size_t)i * 16 * lda + kk);
#pragma unroll
        for (int j = 0; j < NF; j++) bv[j] = *(const bf16x8*)(bp + (size_t)j * 16 * ldb + kk);
    };
    auto mm = [&](bf16x8 (&av)[MF], bf16x8 (&bv)[NF]) {
#pragma unroll
        for (int i = 0; i < MF; i++)
#pragma unroll
            for (int j = 0; j < NF; j++)
                acc[i][j] = __builtin_amdgcn_mfma_f32_16x16x32_bf16(av[i], bv[j], acc[i][j], 0, 0, 0);
    };
    ld(a0, b0, 0);
    if (KI > 1) ld(a1, b1, 32);
#pragma unroll
    for (int s = 0; s < KI; s++) {
        if (s + 2 < KI) {
            const int ml = (s + 2) % 3;
            if (ml == 0) ld(a0, b0, (s + 2) * 32);
            else if (ml == 1) ld(a1, b1, (s + 2) * 32);
            else ld(a2, b2, (s + 2) * 32);
        }
        const int mc = s % 3;
        if (mc == 0) mm(a0, b0);
        else if (mc == 1) mm(a1, b1);
        else mm(a2, b2);
    }
}

// ---------------- Eobs precompute: Eobs[bt][n] = embed_bf[bt] @ W_obs[1024:,:] ----
__global__ __launch_bounds__(256)
void k_eobs(const unsigned short* __restrict__ ebf, const unsigned short* __restrict__ Wt_obs,
            unsigned short* __restrict__ Eobs) {
    int wave = threadIdx.x >> 6, lane = threadIdx.x & 63;
    int row0 = blockIdx.y * 128 + wave * 32, col0 = blockIdx.x * 32;
    f32x4 acc[2][2];
#pragma unroll
    for (int i = 0; i < 2; i++)
#pragma unroll
        for (int j = 0; j < 2; j++) { f32x4 z = {0.f, 0.f, 0.f, 0.f}; acc[i][j] = z; }
    mfma_tile_db<2, 2, 48>(ebf, 1536, Wt_obs + 1024, 2560, row0, col0, acc);
    int lr = lane & 15, q = lane >> 4;
#pragma unroll
    for (int i = 0; i < 2; i++)
#pragma unroll
        for (int j = 0; j < 2; j++)
#pragma unroll
            for (int r = 0; r < 4; r++) {
                int row = row0 + i * 16 + q * 4 + r;
                int col = col0 + j * 16 + lr;
                Eobs[(size_t)row * 1024 + col] = f2bf(acc[i][j][r]);
            }
}

// ---------------- persistent-kernel parameters -----------------------------
struct RP {
    const float* action;
    const float* eps_post;
    const float* eps_prior;
    const unsigned char* is_first;
    const int* ens_idx;
    const float* b_gru;
    const float* ln_g;
    const float* ln_b;
    const float* W_inp;
    const float* b_inp;
    const float* b_obs;
    const float* b_ens;
    const float* Wod;   // W_obs_dist [1024][64]
    const float* bod;
    const float* Wed;   // W_ens_dist [5][1024][64]
    const float* bed;
    const unsigned short* Wt_gru;  // [3072][2048]
    const unsigned short* Wt_obs;  // [1024][2560]
    const unsigned short* Wt_ens;  // [5][1024][1024]
    const unsigned short* Eobs;    // [B*T][1024] bf16
    float* deter;       // [256][1024]
    float* deter_m;     // [256][1024]
    float* G;           // [256][3072] raw GRU GEMM (bias added in gates)
    float* hbuf;        // [256][1024] elu'd ens head
    float* xobuf;       // [256][1024] elu'd obs head
    unsigned short* xcat;    // [288][2048] (32 slop rows for MFMA over-read)
    unsigned short* dnew_bf; // [288][1024]
    float* out;
    char* bar;          // barrier block (zeroed): cnt@0, spack@128, ipack@256+xcd*256
};

// ---------------- island barrier: packed {gen:32 | count:32} at L3 ---------
// No fences: producer stores are in the island's own L2 (write-through L1 +
// vmcnt drain); consumers on the SAME XCD read through that L2; only their
// per-CU L1 can be stale -> buffer_inv (L1-only invalidate) on exit.
__device__ inline void ibar(unsigned long long* pack, unsigned S) {
    __syncthreads();   // compiler emits full s_waitcnt before s_barrier
    if (threadIdx.x == 0) {
        asm volatile("s_waitcnt vmcnt(0)" ::: "memory");
        unsigned long long prev = __hip_atomic_fetch_add(
            pack, 1ull, __ATOMIC_RELAXED, __HIP_MEMORY_SCOPE_AGENT);
        unsigned g = (unsigned)(prev >> 32);
        if ((unsigned)prev == S - 1u) {
            // reset count AND bump gen in one atomic: += (1<<32) - S
            __hip_atomic_fetch_add(pack, (1ull << 32) - (unsigned long long)S,
                                   __ATOMIC_RELAXED, __HIP_MEMORY_SCOPE_AGENT);
        } else {
            long guard = 0;
            while ((unsigned)(__hip_atomic_load(pack, __ATOMIC_RELAXED,
                                                __HIP_MEMORY_SCOPE_AGENT) >> 32) == g) {
                __builtin_amdgcn_s_sleep(2);
                if (++guard > 100000000L) break;   // failsafe: no hang
            }
        }
        asm volatile("buffer_inv" ::: "memory");   // invalidate this CU's L1
    }
    __syncthreads();
}

// ---------------- the island-persistent scan kernel ------------------------
__global__ __launch_bounds__(256, 3)
void rssm_isl(RP P) {
    const int tid = threadIdx.x;
    const int wave = tid >> 6, lane = tid & 63;
    const int lr = lane & 15, q = lane >> 4;

    __shared__ float s_red[4][32][32];                    // 16 KB GEMM reduce
    __shared__ float s_h[1024], s_xo[1024];               // dist inputs
    __shared__ float s_par[256], s_acc[128], s_stoch[32], s_am[8];
    __shared__ float g_r1[4], g_r2[4], g_ms[2];
    __shared__ unsigned sh[4];                            // rank,S,lo,hi

    unsigned* cnt = (unsigned*)P.bar;
    unsigned long long* spack = (unsigned long long*)(P.bar + 128);

    // ---- register with my physical XCD ----
    if (tid == 0) {
        unsigned x;
        asm volatile("s_getreg_b32 %0, hwreg(HW_REG_XCC_ID)" : "=s"(x));
        x &= 7u;
        sh[1] = x;
        sh[0] = __hip_atomic_fetch_add(cnt + x, 1u, __ATOMIC_RELAXED,
                                       __HIP_MEMORY_SCOPE_AGENT);
    }
    __syncthreads();
    const unsigned myxcd = sh[1];
    unsigned long long* ipack = (unsigned long long*)(P.bar + 256 + myxcd * 256);

    // ---- one-time startup barrier (atomic-only data -> no fences needed) ----
    ibar(spack, NBLK);

    if (tid == 0) {
        unsigned pref = 0, Sv = 0, lo = 0, hi = 0;
        for (int i = 0; i < 8; i++) {
            unsigned Si = __hip_atomic_load(cnt + i, __ATOMIC_RELAXED,
                                            __HIP_MEMORY_SCOPE_AGENT);
            if ((unsigned)i == myxcd) {
                Sv = Si;
                lo = (pref * 256u) / 768u;
                hi = ((pref + Si) * 256u) / 768u;
            }
            pref += Si;
        }
        sh[1] = Sv; sh[2] = lo; sh[3] = hi;
    }
    __syncthreads();
    const unsigned rank = sh[0], S = sh[1], lo = sh[2], hi = sh[3];
    const unsigned R = hi - lo;
    const unsigned nsub = (R + 31u) >> 5;

    // ================= phase bodies =================
    auto gru_phase = [&]() {
        for (unsigned jj = rank; jj < 96u * nsub; jj += S) {
            unsigned jc = jj % 96u, sub = jj / 96u;
            int row0 = lo + sub * 32, col0 = jc * 32;
            f32x4 acc[2][2];
#pragma unroll
            for (int i = 0; i < 2; i++)
#pragma unroll
                for (int j = 0; j < 2; j++) { f32x4 z = {0.f,0.f,0.f,0.f}; acc[i][j] = z; }
            // wave-level K-split: wave w covers K [512w, 512w+512)
            mfma_tile_db<2, 2, 16>(P.xcat + wave * 512, 2048,
                                   P.Wt_gru + wave * 512, 2048, row0, col0, acc);
#pragma unroll
            for (int i = 0; i < 2; i++)
#pragma unroll
                for (int j = 0; j < 2; j++)
#pragma unroll
                    for (int r = 0; r < 4; r++)
                        s_red[wave][i * 16 + q * 4 + r][j * 16 + lr] = acc[i][j][r];
            __syncthreads();
            int m = tid * 4, rr = m >> 5, cc = m & 31;
            unsigned grow = row0 + rr;
            if (grow < hi) {
                f32x4 sum;
#pragma unroll
                for (int u = 0; u < 4; u++)
                    sum[u] = s_red[0][rr][cc + u] + s_red[1][rr][cc + u]
                           + s_red[2][rr][cc + u] + s_red[3][rr][cc + u];
                *(f32x4*)(P.G + (size_t)grow * 3072 + col0 + cc) = sum;
            }
            __syncthreads();
        }
    };

    auto gates_phase = [&](int t) {
        for (unsigned jj = rank; jj < R; jj += S) {
            int b = lo + jj;
            const float* Gb = P.G + (size_t)b * 3072;
            float g0[4], g1[4], g2[4];
            float s1 = 0.f, s2 = 0.f;
#pragma unroll
            for (int k = 0; k < 4; k++) {
                int j = tid + k * 256;
                float a0 = Gb[j] + P.b_gru[j];
                float a1 = Gb[j + 1024] + P.b_gru[j + 1024];
                float a2 = Gb[j + 2048] + P.b_gru[j + 2048];
                g0[k] = a0; g1[k] = a1; g2[k] = a2;
                s1 += a0 + a1 + a2;
                s2 += a0 * a0 + a1 * a1 + a2 * a2;
            }
#pragma unroll
            for (int o = 32; o > 0; o >>= 1) {
                s1 += __shfl_down(s1, o, 64); s2 += __shfl_down(s2, o, 64);
            }
            if ((tid & 63) == 0) { g_r1[wave] = s1; g_r2[wave] = s2; }
            __syncthreads();
            if (tid == 0) {
                float a = g_r1[0] + g_r1[1] + g_r1[2] + g_r1[3];
                float c = g_r2[0] + g_r2[1] + g_r2[2] + g_r2[3];
                float mean = a / 3072.f;
                float var = c / 3072.f - mean * mean;
                g_ms[0] = mean; g_ms[1] = rsqrtf(var + 1e-5f);
            }
            __syncthreads();
            float mean = g_ms[0], rstd = g_ms[1];
#pragma unroll
            for (int k = 0; k < 4; k++) {
                int j = tid + k * 256;
                float n0 = (g0[k] - mean) * rstd * P.ln_g[j] + P.ln_b[j];
                float n1 = (g1[k] - mean) * rstd * P.ln_g[j + 1024] + P.ln_b[j + 1024];
                float n2 = (g2[k] - mean) * rstd * P.ln_g[j + 2048] + P.ln_b[j + 2048];
                float reset = sigmoid_f(n0);
                float cand = tanhf(reset * n1);
                float upd = sigmoid_f(n2 - 1.f);   // UPDATE_BIAS = -1
                float dn = upd * cand + (1.f - upd) * P.deter_m[(size_t)b * 1024 + j];
                P.deter[(size_t)b * 1024 + j] = dn;
                P.dnew_bf[(size_t)b * 1024 + j] = f2bf(dn);
                P.out[((size_t)b * T_ + t) * OUTW_ + 192 + j] = dn;
            }
            __syncthreads();
        }
    };

    auto heads_phase = [&](int t) {
        int e = P.ens_idx[t];
        for (unsigned jj = rank; jj < 64u * nsub; jj += S) {
            unsigned jc = jj % 64u, sub = jj / 64u;
            int head = jc >> 5, c32 = jc & 31;
            int row0 = lo + sub * 32, col0 = c32 * 32;
            f32x4 acc[2][2];
#pragma unroll
            for (int i = 0; i < 2; i++)
#pragma unroll
                for (int j = 0; j < 2; j++) { f32x4 z = {0.f,0.f,0.f,0.f}; acc[i][j] = z; }
            // wave-level K-split: wave w covers K [256w, 256w+256)
            if (head == 0)
                mfma_tile_db<2, 2, 8>(P.dnew_bf + wave * 256, 1024,
                                      P.Wt_ens + (size_t)e * 1024 * 1024 + wave * 256, 1024,
                                      row0, col0, acc);
            else
                mfma_tile_db<2, 2, 8>(P.dnew_bf + wave * 256, 1024,
                                      P.Wt_obs + wave * 256, 2560, row0, col0, acc);
#pragma unroll
            for (int i = 0; i < 2; i++)
#pragma unroll
                for (int j = 0; j < 2; j++)
#pragma unroll
                    for (int r = 0; r < 4; r++)
                        s_red[wave][i * 16 + q * 4 + r][j * 16 + lr] = acc[i][j][r];
            __syncthreads();
            int m = tid * 4, rr = m >> 5, cc = m & 31;
            unsigned grow = row0 + rr;
            if (grow < hi) {
#pragma unroll
                for (int u = 0; u < 4; u++) {
                    int col = col0 + cc + u;
                    float sum = s_red[0][rr][cc + u] + s_red[1][rr][cc + u]
                              + s_red[2][rr][cc + u] + s_red[3][rr][cc + u];
                    if (head == 0) {
                        P.hbuf[(size_t)grow * 1024 + col] =
                            elu_f(sum + P.b_ens[(size_t)e * 1024 + col]);
                    } else {
                        float v = sum + P.b_obs[col]
                                + bf2f(P.Eobs[((size_t)grow * T_ + t) * 1024 + col]);
                        P.xobuf[(size_t)grow * 1024 + col] = elu_f(v);
                    }
                }
            }
            __syncthreads();
        }
    };

    auto prep_phase = [&](int t) {
        for (unsigned jj = rank; jj < R; jj += S) {
            int b = lo + jj;
            if (t >= 0) {
                int e = P.ens_idx[t];
                {   // load elu'd heads to LDS (4 f32/thread each)
                    int i = tid * 4;
                    *(f32x4*)(s_h + i)  = *(const f32x4*)(P.hbuf  + (size_t)b * 1024 + i);
                    *(f32x4*)(s_xo + i) = *(const f32x4*)(P.xobuf + (size_t)b * 1024 + i);
                }
                __syncthreads();
                {   // dist matmuls: 128 cols x 2 K-halves
                    int kh = tid >> 7, c = tid & 127;
                    int k0 = kh * 512;
                    float acc = 0.f;
                    if (c < 64) {
                        const float* W = P.Wed + (size_t)e * 65536 + c;
#pragma unroll 8
                        for (int k = 0; k < 512; k++)
                            acc += s_h[k0 + k] * W[(size_t)(k0 + k) * 64];
                    } else {
                        const float* W = P.Wod + (c - 64);
#pragma unroll 8
                        for (int k = 0; k < 512; k++)
                            acc += s_xo[k0 + k] * W[(size_t)(k0 + k) * 64];
                    }
                    s_par[tid] = acc;
                }
                __syncthreads();
                if (tid < 128) {
                    int c = tid & 63;
                    float acc = s_par[tid] + s_par[tid + 128];
                    acc += (tid < 64) ? P.bed[e * 64 + c] : P.bod[c];
                    s_acc[tid] = acc;
                }
                __syncthreads();
                if (tid < 32) {
                    float pm = s_acc[tid];
                    float ps = softplus_f(s_acc[32 + tid]) + 0.1f;
                    float om = s_acc[64 + tid];
                    float os = softplus_f(s_acc[96 + tid]) + 0.1f;
                    size_t bt = (size_t)b * T_ + t;
                    float prior = pm + ps * P.eps_prior[bt * 32 + tid];
                    float post = om + os * P.eps_post[bt * 32 + tid];
                    float* o = P.out + bt * OUTW_;
                    o[tid] = om; o[32 + tid] = os; o[64 + tid] = post;
                    o[96 + tid] = pm; o[128 + tid] = ps; o[160 + tid] = prior;
                    s_stoch[tid] = post;
                }
            } else {
                if (tid < 32) s_stoch[tid] = 0.f;
            }
            int tn = t + 1;
            if (tn < T_) {
                __syncthreads();
                float mq = P.is_first[b * T_ + tn] ? 0.f : 1.f;
                if (tid < ACT_)
                    s_am[tid] = P.action[((size_t)b * T_ + tn) * ACT_ + tid] * mq;
                __syncthreads();
#pragma unroll
                for (int k4 = 0; k4 < 4; k4++) {
                    int n = tid + k4 * 256;
                    float sacc = 0.f;
#pragma unroll
                    for (int k = 0; k < 32; k++) sacc += s_stoch[k] * P.W_inp[k * 1024 + n];
                    float a = P.b_inp[n] + mq * sacc;
#pragma unroll
                    for (int k = 0; k < ACT_; k++) a += s_am[k] * P.W_inp[(32 + k) * 1024 + n];
                    P.xcat[(size_t)b * 2048 + n] = f2bf(elu_f(a));
                    float dv = (t >= 0) ? P.deter[(size_t)b * 1024 + n] : 0.f;
                    float dm = dv * mq;
                    P.deter_m[(size_t)b * 1024 + n] = dm;
                    P.xcat[(size_t)b * 2048 + 1024 + n] = f2bf(dm);
                }
            }
            __syncthreads();
        }
    };

    // ================= the scan =================
    prep_phase(-1);
    ibar(ipack, S);
    for (int t = 0; t < T_; ++t) {
        gru_phase();
        ibar(ipack, S);
        gates_phase(t);
        ibar(ipack, S);
        heads_phase(t);
        ibar(ipack, S);
        prep_phase(t);
        ibar(ipack, S);
    }
}

extern "C" void kernel_launch(void* const* d_in, const int* in_sizes, int n_in,
                              void* d_out, int out_size, void* d_ws, size_t ws_size,
                              hipStream_t stream) {
    const float* embed      = (const float*)d_in[0];
    const float* action     = (const float*)d_in[1];
    const float* eps_post   = (const float*)d_in[2];
    const float* eps_prior  = (const float*)d_in[3];
    const unsigned char* is_first = (const unsigned char*)d_in[4];
    const int* ens_idx      = (const int*)d_in[5];
    const float* W_gru      = (const float*)d_in[6];
    const float* b_gru      = (const float*)d_in[7];
    const float* ln_g       = (const float*)d_in[8];
    const float* ln_b       = (const float*)d_in[9];
    const float* W_inp      = (const float*)d_in[10];
    const float* b_inp      = (const float*)d_in[11];
    const float* W_obs      = (const float*)d_in[12];
    const float* b_obs      = (const float*)d_in[13];
    const float* W_ens      = (const float*)d_in[14];
    const float* b_ens      = (const float*)d_in[15];
    const float* W_obs_dist = (const float*)d_in[16];
    const float* b_obs_dist = (const float*)d_in[17];
    const float* W_ens_dist = (const float*)d_in[18];
    const float* b_ens_dist = (const float*)d_in[19];
    float* out = (float*)d_out;

    char* p = (char*)d_ws;
    auto take = [&](size_t bytes) -> char* {
        char* r = p;
        p += (bytes + 255) & ~(size_t)255;
        return r;
    };
    unsigned short* Wt_gru = (unsigned short*)take((size_t)3072 * 2048 * 2);
    unsigned short* Wt_obs = (unsigned short*)take((size_t)1024 * 2560 * 2);
    unsigned short* Wt_ens = (unsigned short*)take((size_t)5 * 1024 * 1024 * 2);
    float* deter   = (float*)take((size_t)B_ * 1024 * 4);
    float* deter_m = (float*)take((size_t)B_ * 1024 * 4);
    float* G       = (float*)take((size_t)B_ * 3072 * 4);
    float* hbuf    = (float*)take((size_t)B_ * 1024 * 4);
    float* xobuf   = (float*)take((size_t)B_ * 1024 * 4);
    unsigned short* xcat    = (unsigned short*)take((size_t)(B_ + 32) * 2048 * 2);
    unsigned short* dnew_bf = (unsigned short*)take((size_t)(B_ + 32) * 1024 * 2);
    unsigned short* ebf  = (unsigned short*)take((size_t)B_ * T_ * EMBED_ * 2);
    unsigned short* Eobs = (unsigned short*)take((size_t)B_ * T_ * 1024 * 2);
    char* bar = take(4096);
    if ((size_t)(p - (char*)d_ws) > ws_size) return;

    hipMemsetAsync(bar, 0, 4096, stream);

    // ---- one-off precompute ----
    k_transpose_cvt<<<dim3(96, 64, 1), dim3(32, 8), 0, stream>>>(W_gru, Wt_gru, 2048, 3072);
    k_transpose_cvt<<<dim3(32, 80, 1), dim3(32, 8), 0, stream>>>(W_obs, Wt_obs, 2560, 1024);
    k_transpose_cvt<<<dim3(32, 32, 5), dim3(32, 8), 0, stream>>>(W_ens, Wt_ens, 1024, 1024);
    k_convert<<<dim3(2048), dim3(256), 0, stream>>>(embed, ebf, (long)B_ * T_ * EMBED_ / 4);
    k_eobs<<<dim3(32, 128), dim3(256), 0, stream>>>(ebf, Wt_obs, Eobs);

    RP P;
    P.action = action; P.eps_post = eps_post; P.eps_prior = eps_prior;
    P.is_first = is_first; P.ens_idx = ens_idx;
    P.b_gru = b_gru; P.ln_g = ln_g; P.ln_b = ln_b;
    P.W_inp = W_inp; P.b_inp = b_inp; P.b_obs = b_obs; P.b_ens = b_ens;
    P.Wod = W_obs_dist; P.bod = b_obs_dist; P.Wed = W_ens_dist; P.bed = b_ens_dist;
    P.Wt_gru = Wt_gru; P.Wt_obs = Wt_obs; P.Wt_ens = Wt_ens; P.Eobs = Eobs;
    P.deter = deter; P.deter_m = deter_m; P.G = G; P.hbuf = hbuf; P.xobuf = xobuf;
    P.xcat = xcat; P.dnew_bf = dnew_bf; P.out = out; P.bar = bar;

    rssm_isl<<<dim3(NBLK), dim3(256), 0, stream>>>(P);
}